// Round 3
// baseline (250.862 us; speedup 1.0000x reference)
//
#include <hip/hip_runtime.h>

// Single fused kernel, grid=32 (one block per batch), block=1024 (16 waves).
// R0's latency problem is fixed by intra-block parallelism, R2's launch/memset
// overhead is fixed by fusing everything (no ws, no memset, no atomics).
// Rotation is an exact 90-degree permutation (target_l_r in {0..3}).
__global__ __launch_bounds__(1024) void rot_pred_head_fused1(
    const float* __restrict__ z_a,
    const float* __restrict__ z_b,
    const float* __restrict__ cm,
    const float* __restrict__ W1,
    const float* __restrict__ b1,
    const float* __restrict__ W2,
    const float* __restrict__ b2,
    const int* __restrict__ target_l_r,
    const int* __restrict__ loc,
    float* __restrict__ out)
{
    const int b = blockIdx.x;
    const int t = threadIdx.x;

    __shared__ float m[4096];      // 64x64 downsampled (1 - rotated cm)
    __shared__ float sA[512];      // [8][64] pooled za
    __shared__ float sB[512];      // [8][64] pooled zb
    __shared__ float C[64 * 65];   // padded stride 65
    __shared__ float hdn[64];

    // ---- Phase A: mask gather (rotation + nearest-downsample), 4/thread ----
    {
        const int r = target_l_r[b];
        const float* cmb = cm + (size_t)b * 65536;
        #pragma unroll
        for (int it = 0; it < 4; ++it) {
            const int idx = t + (it << 10);
            const int y = idx >> 6, x = idx & 63;
            const int Y = y << 2, X = x << 2;
            int sy, sx;
            if (r == 0)      { sy = Y;       sx = X;       }
            else if (r == 1) { sy = 255 - X; sx = Y;       }
            else if (r == 2) { sy = 255 - Y; sx = 255 - X; }
            else             { sy = X;       sx = 255 - Y; }
            m[idx] = 1.0f - cmb[sy * 256 + sx];
        }
    }
    __syncthreads();

    // ---- Phase B: masked 8x8 avg-pool, all 8 features concurrently ----
    {
        const int f    = t >> 7;          // 0..7
        const int r128 = t & 127;
        const int cell = r128 >> 1;       // 0..63
        const int sub  = r128 & 1;        // 2 lanes per cell
        const int py = cell >> 3, px = cell & 7;
        const int row0 = py * 8 + sub * 4;        // 4 rows x 8 cols per lane
        const int cbase = px * 8;

        const size_t zoff = ((size_t)(b * 256 + loc[f])) * 4096;
        const float* pa = z_a + zoff;
        const float* pb = z_b + zoff;

        float sa = 0.0f, sb = 0.0f;
        #pragma unroll
        for (int rr = 0; rr < 4; ++rr) {
            const int base = (row0 + rr) * 64 + cbase;
            const float4 a0 = *(const float4*)(pa + base);
            const float4 a1 = *(const float4*)(pa + base + 4);
            const float4 b0 = *(const float4*)(pb + base);
            const float4 b1v = *(const float4*)(pb + base + 4);
            const float4 m0 = *(const float4*)(m + base);
            const float4 m1 = *(const float4*)(m + base + 4);
            sa += a0.x*m0.x + a0.y*m0.y + a0.z*m0.z + a0.w*m0.w
                + a1.x*m1.x + a1.y*m1.y + a1.z*m1.z + a1.w*m1.w;
            sb += b0.x*m0.x + b0.y*m0.y + b0.z*m0.z + b0.w*m0.w
                + b1v.x*m1.x + b1v.y*m1.y + b1v.z*m1.z + b1v.w*m1.w;
        }
        sa += __shfl_xor(sa, 1);
        sb += __shfl_xor(sb, 1);
        if (sub == 0) {
            sA[(f << 6) + cell] = sa * 0.015625f;   // /64
            sB[(f << 6) + cell] = sb * 0.015625f;
        }
    }
    __syncthreads();

    // ---- Phase C: C[i][j] = sum_f sA[f][i]*sB[f][j], 4 entries/thread ----
    #pragma unroll
    for (int it = 0; it < 4; ++it) {
        const int k = t + (it << 10);
        const int i = k >> 6, j = k & 63;
        float acc = 0.0f;
        #pragma unroll
        for (int f = 0; f < 8; ++f)
            acc += sA[(f << 6) + i] * sB[(f << 6) + j];
        C[i * 65 + j] = acc;
    }
    __syncthreads();

    // ---- Phase D: softmax down each column j, 16 lanes/column ----
    {
        const int j = t >> 4, sub = t & 15;
        float v0 = C[(sub     ) * 65 + j];
        float v1 = C[(sub + 16) * 65 + j];
        float v2 = C[(sub + 32) * 65 + j];
        float v3 = C[(sub + 48) * 65 + j];
        float mx = fmaxf(fmaxf(v0, v1), fmaxf(v2, v3));
        mx = fmaxf(mx, __shfl_xor(mx, 1));
        mx = fmaxf(mx, __shfl_xor(mx, 2));
        mx = fmaxf(mx, __shfl_xor(mx, 4));
        mx = fmaxf(mx, __shfl_xor(mx, 8));
        v0 = expf(v0 - mx); v1 = expf(v1 - mx);
        v2 = expf(v2 - mx); v3 = expf(v3 - mx);
        float s = (v0 + v1) + (v2 + v3);
        s += __shfl_xor(s, 1);
        s += __shfl_xor(s, 2);
        s += __shfl_xor(s, 4);
        s += __shfl_xor(s, 8);
        const float inv = 1.0f / s;
        C[(sub     ) * 65 + j] = v0 * inv;
        C[(sub + 16) * 65 + j] = v1 * inv;
        C[(sub + 32) * 65 + j] = v2 * inv;
        C[(sub + 48) * 65 + j] = v3 * inv;
    }
    __syncthreads();

    // ---- Phase E: hdn = relu(softC @ W1^T + b1), 16 lanes/output ----
    {
        const int o = t >> 4, sub = t & 15;
        const float* w = W1 + (size_t)o * 4096;
        float acc0 = 0.f, acc1 = 0.f;
        #pragma unroll 8
        for (int it = 0; it < 64; it += 2) {
            const int k0 = (sub + (it << 4)) << 2;       // float4-aligned, in-row
            const int k1 = (sub + ((it + 1) << 4)) << 2;
            const float4 w0 = *(const float4*)(w + k0);
            const float4 w1 = *(const float4*)(w + k1);
            const float* c0 = &C[(k0 >> 6) * 65 + (k0 & 63)];
            const float* c1 = &C[(k1 >> 6) * 65 + (k1 & 63)];
            acc0 += w0.x * c0[0] + w0.y * c0[1] + w0.z * c0[2] + w0.w * c0[3];
            acc1 += w1.x * c1[0] + w1.y * c1[1] + w1.z * c1[2] + w1.w * c1[3];
        }
        float acc = acc0 + acc1;
        acc += __shfl_xor(acc, 1);
        acc += __shfl_xor(acc, 2);
        acc += __shfl_xor(acc, 4);
        acc += __shfl_xor(acc, 8);
        if (sub == 0) hdn[o] = fmaxf(acc + b1[o], 0.0f);
    }
    __syncthreads();

    // ---- Phase F: out = hdn @ W2^T + b2 ----
    if (t < 4) {
        float acc = b2[t];
        #pragma unroll
        for (int o = 0; o < 64; ++o) acc += hdn[o] * W2[t * 64 + o];
        out[b * 4 + t] = acc;
    }
}

extern "C" void kernel_launch(void* const* d_in, const int* in_sizes, int n_in,
                              void* d_out, int out_size, void* d_ws, size_t ws_size,
                              hipStream_t stream) {
    const float* z_a = (const float*)d_in[0];
    const float* z_b = (const float*)d_in[1];
    const float* cm  = (const float*)d_in[2];
    const float* W1  = (const float*)d_in[3];
    const float* b1  = (const float*)d_in[4];
    const float* W2  = (const float*)d_in[5];
    const float* b2  = (const float*)d_in[6];
    const int* rot   = (const int*)d_in[7];
    const int* loc   = (const int*)d_in[8];
    float* out = (float*)d_out;

    hipLaunchKernelGGL(rot_pred_head_fused1, dim3(32), dim3(1024), 0, stream,
                       z_a, z_b, cm, W1, b1, W2, b2, rot, loc, out);
}